// Round 1
// baseline (209.683 us; speedup 1.0000x reference)
//
#include <hip/hip_runtime.h>

typedef unsigned short u16;
typedef unsigned int u32;
typedef __bf16 bf16x8 __attribute__((ext_vector_type(8)));
typedef float f32x4 __attribute__((ext_vector_type(4)));

// workspace layout (bytes)
#define OFF_G      0x000000   // 8*32*256 f32      = 256 KB
#define OFF_AW     0x040000   // 8*8*4096 f32      = 1 MB
#define OFF_WT     0x140000   // 256*2304 bf16     = 1.125 MB
#define OFF_SHIFT  0x260000   // 256 f32
#define OFF_XB     0x270000   // 8*256*4096 bf16   = 16 MB
#define WS_NEED_XB (0x270000 + 16777216)

__device__ __forceinline__ u16 f2bf(float f) {
  union { float f; u32 u; } v; v.f = f;
  return (u16)((v.u + 0x7FFFu + ((v.u >> 16) & 1u)) >> 16);
}

// ---- weight prep: Wt[co][t*256+ci] = bf16(w[co][ci][t] * inv[co]); shift[co] ----
__global__ void wprep_k(const float* __restrict__ w, const float* __restrict__ gamma,
                        const float* __restrict__ beta, const float* __restrict__ mean,
                        const float* __restrict__ var, u16* __restrict__ wt,
                        float* __restrict__ shift) {
  const int co = blockIdx.x / 9;
  const int t  = blockIdx.x % 9;
  const int ci = threadIdx.x;
  const float inv = gamma[co] / sqrtf(var[co] + 1e-3f);
  wt[co * 2304 + t * 256 + ci] = f2bf(w[(co * 256 + ci) * 9 + t] * inv);
  if (t == 0 && ci == 0) shift[co] = beta[co] - mean[co] * inv;
}

// ---- x -> bf16 ----
__global__ void xb_k(const float* __restrict__ x, u16* __restrict__ xb) {
  const int i = blockIdx.x * 256 + threadIdx.x;  // over 2,097,152 float4s
  const float4 v = ((const float4*)x)[i];
  ushort4 o;
  o.x = f2bf(v.x); o.y = f2bf(v.y); o.z = f2bf(v.z); o.w = f2bf(v.w);
  ((ushort4*)xb)[i] = o;
}

// ---- guide projection: g[b,n,e] = guide[b,n,:] . gl_w[e,:] + gl_b[e] ----
__global__ void gproj_k(const float* __restrict__ guide, const float* __restrict__ glw,
                        const float* __restrict__ glb, float* __restrict__ g) {
  __shared__ float gr[512];
  const int bn = blockIdx.x;          // 0..255 = b*32+n
  const int e  = threadIdx.x;         // 0..255
  gr[e]       = guide[bn * 512 + e];
  gr[e + 256] = guide[bn * 512 + 256 + e];
  __syncthreads();
  float acc = glb[e];
  const float4* wr  = (const float4*)(glw + (size_t)e * 512);
  const float4* gr4 = (const float4*)gr;
#pragma unroll 8
  for (int i = 0; i < 128; ++i) {
    const float4 a = wr[i], b4 = gr4[i];
    acc = fmaf(a.x, b4.x, acc);
    acc = fmaf(a.y, b4.y, acc);
    acc = fmaf(a.z, b4.z, acc);
    acc = fmaf(a.w, b4.w, acc);
  }
  g[bn * 256 + e] = acc;
}

// ---- attention weights: aw[b,m,p] = sigmoid(max_n dot_c(x[b,m*32+c,p], g[b,n,m,c])/sqrt(32)+bias[m]) ----
__global__ void attnw_k(const float* __restrict__ x, const float* __restrict__ g,
                        const float* __restrict__ bias, float* __restrict__ aw) {
  const int bm = blockIdx.x;          // b*8+m
  const int b = bm >> 3, m = bm & 7;
  const int p = blockIdx.y * 256 + threadIdx.x;
  const float* xp = x + (size_t)(b * 256 + m * 32) * 4096 + p;
  float xv[32];
#pragma unroll
  for (int c = 0; c < 32; ++c) xv[c] = xp[(size_t)c * 4096];
  const float* gv = g + b * 8192 + m * 32;   // + n*256 + c, wave-uniform -> s_load
  float best = -3.4e38f;
#pragma unroll 4
  for (int n = 0; n < 32; ++n) {
    const float* grow = gv + n * 256;
    float s = 0.f;
#pragma unroll
    for (int c = 0; c < 32; ++c) s = fmaf(xv[c], grow[c], s);
    best = fmaxf(best, s);
  }
  const float z = best * 0.17677669529663687f + bias[m];
  aw[(size_t)bm * 4096 + p] = 1.f / (1.f + expf(-z));
}

// ---- conv 3x3 implicit GEMM, bf16 MFMA, fused BN + attn multiply ----
#define LDK 72  // padded LDS row (64 + 8 bf16) = 144 B, 16B-aligned

__global__ __launch_bounds__(256) void conv_k(
    const float* __restrict__ xf, const u16* __restrict__ xb,
    const u16* __restrict__ wt, const float* __restrict__ shift,
    const float* __restrict__ aw, float* __restrict__ out, int useb) {
  __shared__ u16 As[128 * LDK];
  __shared__ u16 Bs[128 * LDK];

  const int tid  = threadIdx.x;
  const int lane = tid & 63;
  const int wave = tid >> 6;
  const int wm = wave >> 1, wn = wave & 1;
  const int p0  = blockIdx.x * 128;     // pixel tile base (within b*4096..)
  const int co0 = blockIdx.y * 128;     // out-channel tile base
  const int b   = p0 >> 12;
  const int y0  = (p0 >> 6) & 63;

  // B staging mapping: thread -> (pixel-in-tile, k-half)
  const int bn   = tid & 127;
  const int half = tid >> 7;
  const int py = y0 + (bn >> 6);
  const int px = bn & 63;
  const long xbase = (long)b * (256L * 4096L);

  // A staging mapping: chunk = tid + q*256 -> row = tid>>3 + q*32, kc = tid&7
  const int arow0 = tid >> 3;
  const int akc   = tid & 7;

  f32x4 acc[4][4];
#pragma unroll
  for (int i = 0; i < 4; ++i)
#pragma unroll
    for (int j = 0; j < 4; ++j) acc[i][j] = (f32x4){0.f, 0.f, 0.f, 0.f};

  for (int t = 0; t < 9; ++t) {
    const int dy = t / 3 - 1, dxx = t % 3 - 1;
    const int yy = py + dy, xg = px + dxx;
    const bool valid = ((unsigned)yy < 64u) && ((unsigned)xg < 64u);
    const long pixoff = xbase + (long)yy * 64 + xg;

    for (int ci0 = 0; ci0 < 256; ci0 += 64) {
      const int kbase = t * 256 + ci0;
      // ---- stage A (weights) ----
#pragma unroll
      for (int q = 0; q < 4; ++q) {
        const int row = arow0 + q * 32;
        const uint4 v = *(const uint4*)(wt + (size_t)(co0 + row) * 2304 + kbase + akc * 8);
        *(uint4*)(&As[row * LDK + akc * 8]) = v;
      }
      // ---- stage B (im2col patches) ----
      {
        u32 vals[16];
        const int chb = ci0 + half * 32;
        if (useb) {
#pragma unroll
          for (int jj = 0; jj < 16; ++jj) {
            const u16 lo = valid ? xb[pixoff + (long)(chb + jj * 2) * 4096] : (u16)0;
            const u16 hi = valid ? xb[pixoff + (long)(chb + jj * 2 + 1) * 4096] : (u16)0;
            vals[jj] = (u32)lo | ((u32)hi << 16);
          }
        } else {
#pragma unroll
          for (int jj = 0; jj < 16; ++jj) {
            const float lo = valid ? xf[pixoff + (long)(chb + jj * 2) * 4096] : 0.f;
            const float hi = valid ? xf[pixoff + (long)(chb + jj * 2 + 1) * 4096] : 0.f;
            vals[jj] = (u32)f2bf(lo) | ((u32)f2bf(hi) << 16);
          }
        }
#pragma unroll
        for (int q = 0; q < 4; ++q) {
          uint4 v; v.x = vals[q*4]; v.y = vals[q*4+1]; v.z = vals[q*4+2]; v.w = vals[q*4+3];
          *(uint4*)(&Bs[bn * LDK + half * 32 + q * 8]) = v;
        }
      }
      __syncthreads();
      // ---- compute ----
#pragma unroll
      for (int ks = 0; ks < 2; ++ks) {
        const int coloff = ks * 32 + (lane >> 4) * 8;
        bf16x8 af[4], bfr[4];
#pragma unroll
        for (int mi = 0; mi < 4; ++mi)
          af[mi] = *(const bf16x8*)(&As[(wm * 64 + mi * 16 + (lane & 15)) * LDK + coloff]);
#pragma unroll
        for (int ni = 0; ni < 4; ++ni)
          bfr[ni] = *(const bf16x8*)(&Bs[(wn * 64 + ni * 16 + (lane & 15)) * LDK + coloff]);
#pragma unroll
        for (int mi = 0; mi < 4; ++mi)
#pragma unroll
          for (int ni = 0; ni < 4; ++ni)
            acc[mi][ni] = __builtin_amdgcn_mfma_f32_16x16x32_bf16(af[mi], bfr[ni], acc[mi][ni], 0, 0, 0);
      }
      __syncthreads();
    }
  }

  // ---- epilogue: out = (conv*inv + shift) * aw ----
  const int pybase = p0 & 4095;
#pragma unroll
  for (int mi = 0; mi < 4; ++mi) {
#pragma unroll
    for (int j = 0; j < 4; ++j) {
      const int co = co0 + wm * 64 + mi * 16 + ((lane >> 4) << 2) + j;
      const float sh = shift[co];
      const float* awrow = aw + (size_t)(b * 8 + (co >> 5)) * 4096 + pybase;
      float* orow = out + (size_t)(b * 256 + co) * 4096 + pybase;
#pragma unroll
      for (int ni = 0; ni < 4; ++ni) {
        const int pp = wn * 64 + ni * 16 + (lane & 15);
        orow[pp] = (acc[mi][ni][j] + sh) * awrow[pp];
      }
    }
  }
}

extern "C" void kernel_launch(void* const* d_in, const int* in_sizes, int n_in,
                              void* d_out, int out_size, void* d_ws, size_t ws_size,
                              hipStream_t stream) {
  (void)in_sizes; (void)n_in; (void)out_size;
  const float* x     = (const float*)d_in[0];
  const float* guide = (const float*)d_in[1];
  const float* glw   = (const float*)d_in[2];
  const float* glb   = (const float*)d_in[3];
  const float* bias  = (const float*)d_in[4];
  const float* pw    = (const float*)d_in[5];
  const float* gamma = (const float*)d_in[6];
  const float* beta  = (const float*)d_in[7];
  const float* mean  = (const float*)d_in[8];
  const float* var   = (const float*)d_in[9];
  float* out = (float*)d_out;

  char* ws = (char*)d_ws;
  float* g     = (float*)(ws + OFF_G);
  float* aw    = (float*)(ws + OFF_AW);
  u16*   wt    = (u16*)(ws + OFF_WT);
  float* shift = (float*)(ws + OFF_SHIFT);
  u16*   xb    = (u16*)(ws + OFF_XB);
  const int useb = (ws_size >= (size_t)WS_NEED_XB) ? 1 : 0;

  wprep_k<<<dim3(2304), dim3(256), 0, stream>>>(pw, gamma, beta, mean, var, wt, shift);
  if (useb) xb_k<<<dim3(8192), dim3(256), 0, stream>>>(x, xb);
  gproj_k<<<dim3(256), dim3(256), 0, stream>>>(guide, glw, glb, g);
  attnw_k<<<dim3(64, 16), dim3(256), 0, stream>>>(x, g, bias, aw);
  conv_k<<<dim3(256, 2), dim3(256), 0, stream>>>(x, xb, wt, shift, aw, out, useb);
}

// Round 2
// 102.787 us; speedup vs baseline: 2.0400x; 2.0400x over previous
//
#include <hip/hip_runtime.h>

typedef unsigned short u16;
typedef unsigned int u32;
typedef __bf16 bf16x8 __attribute__((ext_vector_type(8)));
typedef float f32x4 __attribute__((ext_vector_type(4)));

// workspace layout (bytes)
#define OFF_G      0x000000   // 8*32*256 f32
#define OFF_AW     0x040000   // 8*8*4096 f32
#define OFF_WT     0x140000   // 256*2304 bf16
#define OFF_SHIFT  0x260000   // 256 f32
#define OFF_XPAD   0x270000   // 8*66*66*256 bf16 (zero-padded NHWC)
#define XPAD_BYTES (8u*66u*66u*256u*2u)
#define WS_NEED    ((size_t)OFF_XPAD + (size_t)XPAD_BYTES)

__device__ __forceinline__ u16 f2bf(float f) {
  union { float f; u32 u; } v; v.f = f;
  return (u16)((v.u + 0x7FFFu + ((v.u >> 16) & 1u)) >> 16);
}

__device__ __forceinline__ void gl2lds16(const u16* g, u16* l) {
  __builtin_amdgcn_global_load_lds(
      (const __attribute__((address_space(1))) void*)g,
      (__attribute__((address_space(3))) void*)l, 16, 0, 0);
}

// ---- weight prep: Wt[co][t*256+ci] = bf16(w[co][ci][t] * inv[co]); shift[co] ----
__global__ void wprep_k(const float* __restrict__ w, const float* __restrict__ gamma,
                        const float* __restrict__ beta, const float* __restrict__ mean,
                        const float* __restrict__ var, u16* __restrict__ wt,
                        float* __restrict__ shift) {
  const int co = blockIdx.x / 9;
  const int t  = blockIdx.x % 9;
  const int ci = threadIdx.x;
  const float inv = gamma[co] / sqrtf(var[co] + 1e-3f);
  wt[co * 2304 + t * 256 + ci] = f2bf(w[(co * 256 + ci) * 9 + t] * inv);
  if (t == 0 && ci == 0) shift[co] = beta[co] - mean[co] * inv;
}

// ---- zero the padded NHWC buffer (border must be 0 every call) ----
__global__ void zero_k(uint4* __restrict__ p) {
  p[(size_t)blockIdx.x * 256 + threadIdx.x] = (uint4){0, 0, 0, 0};
}

// ---- x (NCHW f32) -> xpad (padded NHWC bf16) via LDS transpose ----
__global__ void xpad_k(const float* __restrict__ x, u16* __restrict__ xp) {
  __shared__ u16 tile[256][68];
  const int tid = threadIdx.x;
  const int b = blockIdx.x >> 6, y = blockIdx.x & 63;
  const int cb = tid >> 4, xq = tid & 15;
#pragma unroll
  for (int i = 0; i < 16; ++i) {
    const int c = i * 16 + cb;
    const float4 v = *(const float4*)(x + (size_t)(b * 256 + c) * 4096 + y * 64 + xq * 4);
    ushort4 o; o.x = f2bf(v.x); o.y = f2bf(v.y); o.z = f2bf(v.z); o.w = f2bf(v.w);
    *(ushort4*)(&tile[c][xq * 4]) = o;
  }
  __syncthreads();
  const int px = tid & 63, cg = tid >> 6;
  u16* dst = xp + ((size_t)(b * 66 + y + 1) * 66 + px + 1) * 256 + cg * 64;
  u32 wbuf[32];
#pragma unroll
  for (int j = 0; j < 32; ++j) {
    const u16 lo = tile[cg * 64 + 2 * j][px];
    const u16 hi = tile[cg * 64 + 2 * j + 1][px];
    wbuf[j] = (u32)lo | ((u32)hi << 16);
  }
#pragma unroll
  for (int q = 0; q < 8; ++q) {
    uint4 v; v.x = wbuf[q * 4]; v.y = wbuf[q * 4 + 1]; v.z = wbuf[q * 4 + 2]; v.w = wbuf[q * 4 + 3];
    *(uint4*)(dst + q * 8) = v;
  }
}

// ---- guide projection ----
__global__ void gproj_k(const float* __restrict__ guide, const float* __restrict__ glw,
                        const float* __restrict__ glb, float* __restrict__ g) {
  __shared__ float gr[512];
  const int bn = blockIdx.x;
  const int e  = threadIdx.x;
  gr[e]       = guide[bn * 512 + e];
  gr[e + 256] = guide[bn * 512 + 256 + e];
  __syncthreads();
  float acc = glb[e];
  const float4* wr  = (const float4*)(glw + (size_t)e * 512);
  const float4* gr4 = (const float4*)gr;
#pragma unroll 8
  for (int i = 0; i < 128; ++i) {
    const float4 a = wr[i], b4 = gr4[i];
    acc = fmaf(a.x, b4.x, acc);
    acc = fmaf(a.y, b4.y, acc);
    acc = fmaf(a.z, b4.z, acc);
    acc = fmaf(a.w, b4.w, acc);
  }
  g[bn * 256 + e] = acc;
}

// ---- attention weights ----
__global__ void attnw_k(const float* __restrict__ x, const float* __restrict__ g,
                        const float* __restrict__ bias, float* __restrict__ aw) {
  const int bm = blockIdx.x;
  const int b = bm >> 3, m = bm & 7;
  const int p = blockIdx.y * 256 + threadIdx.x;
  const float* xp = x + (size_t)(b * 256 + m * 32) * 4096 + p;
  float xv[32];
#pragma unroll
  for (int c = 0; c < 32; ++c) xv[c] = xp[(size_t)c * 4096];
  const float* gv = g + b * 8192 + m * 32;
  float best = -3.4e38f;
#pragma unroll 4
  for (int n = 0; n < 32; ++n) {
    const float* grow = gv + n * 256;
    float s = 0.f;
#pragma unroll
    for (int c = 0; c < 32; ++c) s = fmaf(xv[c], grow[c], s);
    best = fmaxf(best, s);
  }
  const float z = best * 0.17677669529663687f + bias[m];
  aw[(size_t)bm * 4096 + p] = 1.f / (1.f + expf(-z));
}

// ---- conv 3x3 implicit GEMM (m97 structure): global_load_lds w16, XOR-swizzled LDS ----
__global__ __launch_bounds__(256) void conv_k(
    const u16* __restrict__ xp, const u16* __restrict__ wt,
    const float* __restrict__ shift, const float* __restrict__ aw,
    float* __restrict__ out) {
  __shared__ u16 As[128 * 64];
  __shared__ u16 Bs[128 * 64];

  const int tid  = threadIdx.x;
  const int lane = tid & 63;
  const int wave = tid >> 6;
  const int wm = wave >> 1, wn = wave & 1;
  const int p0  = blockIdx.x * 128;
  const int co0 = blockIdx.y * 128;
  const int b   = blockIdx.x >> 5;
  const int y0  = (p0 >> 6) & 63;

  // staging: lane -> (row-in-8-group, pre-swizzled logical 16B chunk)
  const int srow   = lane >> 3;
  const int lchunk = (lane & 7) ^ srow;   // inverse-swizzled SOURCE (rule 21)

  const u16* agp[4];
  const u16* bgp[4];
#pragma unroll
  for (int q = 0; q < 4; ++q) {
    const int r = (q * 4 + wave) * 8 + srow;
    agp[q] = wt + (size_t)(co0 + r) * 2304 + lchunk * 8;
    const int py = y0 + (r >> 6), px = r & 63;
    bgp[q] = xp + ((size_t)(b * 66 + py + 1) * 66 + px + 1) * 256 + lchunk * 8;
  }

  f32x4 acc[4][4];
#pragma unroll
  for (int i = 0; i < 4; ++i)
#pragma unroll
    for (int j = 0; j < 4; ++j) acc[i][j] = (f32x4){0.f, 0.f, 0.f, 0.f};

  for (int t = 0; t < 9; ++t) {
    const int dy = t / 3 - 1, dxx = t % 3 - 1;
    const int aof = t * 256;
    const int bof = (dy * 66 + dxx) * 256;
#pragma unroll
    for (int ci0 = 0; ci0 < 256; ci0 += 64) {
#pragma unroll
      for (int q = 0; q < 4; ++q)
        gl2lds16(agp[q] + aof + ci0, &As[(q * 4 + wave) * 512]);
#pragma unroll
      for (int q = 0; q < 4; ++q)
        gl2lds16(bgp[q] + bof + ci0, &Bs[(q * 4 + wave) * 512]);
      __syncthreads();   // drains vmcnt, all waves' staging complete
#pragma unroll
      for (int ks = 0; ks < 2; ++ks) {
        const int slot = ((ks << 2) | (lane >> 4)) ^ (lane & 7);  // swizzled READ
        bf16x8 af[4], bfr[4];
#pragma unroll
        for (int mi = 0; mi < 4; ++mi) {
          const int r = wm * 64 + mi * 16 + (lane & 15);
          af[mi] = *(const bf16x8*)(&As[r * 64 + slot * 8]);
        }
#pragma unroll
        for (int ni = 0; ni < 4; ++ni) {
          const int r = wn * 64 + ni * 16 + (lane & 15);
          bfr[ni] = *(const bf16x8*)(&Bs[r * 64 + slot * 8]);
        }
#pragma unroll
        for (int mi = 0; mi < 4; ++mi)
#pragma unroll
          for (int ni = 0; ni < 4; ++ni)
            acc[mi][ni] = __builtin_amdgcn_mfma_f32_16x16x32_bf16(af[mi], bfr[ni], acc[mi][ni], 0, 0, 0);
      }
      __syncthreads();
    }
  }

  // ---- epilogue: out = (conv + shift) * aw ----
  const int pybase = p0 & 4095;
#pragma unroll
  for (int mi = 0; mi < 4; ++mi) {
#pragma unroll
    for (int j = 0; j < 4; ++j) {
      const int co = co0 + wm * 64 + mi * 16 + ((lane >> 4) << 2) + j;
      const float sh = shift[co];
      const float* awrow = aw + (size_t)(b * 8 + (co >> 5)) * 4096 + pybase;
      float* orow = out + (size_t)(b * 256 + co) * 4096 + pybase;
#pragma unroll
      for (int ni = 0; ni < 4; ++ni) {
        const int pp = wn * 64 + ni * 16 + (lane & 15);
        orow[pp] = (acc[mi][ni][j] + sh) * awrow[pp];
      }
    }
  }
}

// ---- fallback conv (f32 direct reads, predicated) if ws too small for xpad ----
#define LDK 72
__global__ __launch_bounds__(256) void conv_fb(
    const float* __restrict__ xf, const u16* __restrict__ wt,
    const float* __restrict__ shift, const float* __restrict__ aw,
    float* __restrict__ out) {
  __shared__ u16 As[128 * LDK];
  __shared__ u16 Bs[128 * LDK];
  const int tid  = threadIdx.x;
  const int lane = tid & 63;
  const int wave = tid >> 6;
  const int wm = wave >> 1, wn = wave & 1;
  const int p0  = blockIdx.x * 128;
  const int co0 = blockIdx.y * 128;
  const int b   = p0 >> 12;
  const int y0  = (p0 >> 6) & 63;
  const int bn   = tid & 127;
  const int half = tid >> 7;
  const int py = y0 + (bn >> 6);
  const int px = bn & 63;
  const long xbase = (long)b * (256L * 4096L);
  const int arow0 = tid >> 3;
  const int akc   = tid & 7;

  f32x4 acc[4][4];
#pragma unroll
  for (int i = 0; i < 4; ++i)
#pragma unroll
    for (int j = 0; j < 4; ++j) acc[i][j] = (f32x4){0.f, 0.f, 0.f, 0.f};

  for (int t = 0; t < 9; ++t) {
    const int dy = t / 3 - 1, dxx = t % 3 - 1;
    const int yy = py + dy, xg = px + dxx;
    const bool valid = ((unsigned)yy < 64u) && ((unsigned)xg < 64u);
    const long pixoff = xbase + (long)yy * 64 + xg;
    for (int ci0 = 0; ci0 < 256; ci0 += 64) {
      const int kbase = t * 256 + ci0;
#pragma unroll
      for (int q = 0; q < 4; ++q) {
        const int row = arow0 + q * 32;
        const uint4 v = *(const uint4*)(wt + (size_t)(co0 + row) * 2304 + kbase + akc * 8);
        *(uint4*)(&As[row * LDK + akc * 8]) = v;
      }
      {
        u32 vals[16];
        const int chb = ci0 + half * 32;
#pragma unroll
        for (int jj = 0; jj < 16; ++jj) {
          const float lo = valid ? xf[pixoff + (long)(chb + jj * 2) * 4096] : 0.f;
          const float hi = valid ? xf[pixoff + (long)(chb + jj * 2 + 1) * 4096] : 0.f;
          vals[jj] = (u32)f2bf(lo) | ((u32)f2bf(hi) << 16);
        }
#pragma unroll
        for (int q = 0; q < 4; ++q) {
          uint4 v; v.x = vals[q*4]; v.y = vals[q*4+1]; v.z = vals[q*4+2]; v.w = vals[q*4+3];
          *(uint4*)(&Bs[bn * LDK + half * 32 + q * 8]) = v;
        }
      }
      __syncthreads();
#pragma unroll
      for (int ks = 0; ks < 2; ++ks) {
        const int coloff = ks * 32 + (lane >> 4) * 8;
        bf16x8 af[4], bfr[4];
#pragma unroll
        for (int mi = 0; mi < 4; ++mi)
          af[mi] = *(const bf16x8*)(&As[(wm * 64 + mi * 16 + (lane & 15)) * LDK + coloff]);
#pragma unroll
        for (int ni = 0; ni < 4; ++ni)
          bfr[ni] = *(const bf16x8*)(&Bs[(wn * 64 + ni * 16 + (lane & 15)) * LDK + coloff]);
#pragma unroll
        for (int mi = 0; mi < 4; ++mi)
#pragma unroll
          for (int ni = 0; ni < 4; ++ni)
            acc[mi][ni] = __builtin_amdgcn_mfma_f32_16x16x32_bf16(af[mi], bfr[ni], acc[mi][ni], 0, 0, 0);
      }
      __syncthreads();
    }
  }
  const int pybase = p0 & 4095;
#pragma unroll
  for (int mi = 0; mi < 4; ++mi) {
#pragma unroll
    for (int j = 0; j < 4; ++j) {
      const int co = co0 + wm * 64 + mi * 16 + ((lane >> 4) << 2) + j;
      const float sh = shift[co];
      const float* awrow = aw + (size_t)(b * 8 + (co >> 5)) * 4096 + pybase;
      float* orow = out + (size_t)(b * 256 + co) * 4096 + pybase;
#pragma unroll
      for (int ni = 0; ni < 4; ++ni) {
        const int pp = wn * 64 + ni * 16 + (lane & 15);
        orow[pp] = (acc[mi][ni][j] + sh) * awrow[pp];
      }
    }
  }
}

extern "C" void kernel_launch(void* const* d_in, const int* in_sizes, int n_in,
                              void* d_out, int out_size, void* d_ws, size_t ws_size,
                              hipStream_t stream) {
  (void)in_sizes; (void)n_in; (void)out_size;
  const float* x     = (const float*)d_in[0];
  const float* guide = (const float*)d_in[1];
  const float* glw   = (const float*)d_in[2];
  const float* glb   = (const float*)d_in[3];
  const float* bias  = (const float*)d_in[4];
  const float* pw    = (const float*)d_in[5];
  const float* gamma = (const float*)d_in[6];
  const float* beta  = (const float*)d_in[7];
  const float* mean  = (const float*)d_in[8];
  const float* var   = (const float*)d_in[9];
  float* out = (float*)d_out;

  char* ws = (char*)d_ws;
  float* g     = (float*)(ws + OFF_G);
  float* aw    = (float*)(ws + OFF_AW);
  u16*   wt    = (u16*)(ws + OFF_WT);
  float* shift = (float*)(ws + OFF_SHIFT);
  u16*   xpad  = (u16*)(ws + OFF_XPAD);
  const int usexp = (ws_size >= WS_NEED) ? 1 : 0;

  wprep_k<<<dim3(2304), dim3(256), 0, stream>>>(pw, gamma, beta, mean, var, wt, shift);
  if (usexp) {
    zero_k<<<dim3(4356), dim3(256), 0, stream>>>((uint4*)xpad);
    xpad_k<<<dim3(512), dim3(256), 0, stream>>>(x, xpad);
  }
  gproj_k<<<dim3(256), dim3(256), 0, stream>>>(guide, glw, glb, g);
  attnw_k<<<dim3(64, 16), dim3(256), 0, stream>>>(x, g, bias, aw);
  if (usexp)
    conv_k<<<dim3(256, 2), dim3(256), 0, stream>>>(xpad, wt, shift, aw, out);
  else
    conv_fb<<<dim3(256, 2), dim3(256), 0, stream>>>(x, wt, shift, aw, out);
}